// Round 4
// baseline (1405.309 us; speedup 1.0000x reference)
//
#include <hip/hip_runtime.h>

#define NN 100000
#define EE 1000000
#define NFEAT 512
#define NHID 32
#define HEADS 8
#define F1 256               // HEADS*NHID
#define NCLASS 40
#define SLOPE 0.2f
#define NB1 98               // ceil(NN/1024) scan blocks

typedef __bf16 bf16x8 __attribute__((ext_vector_type(8)));
typedef float f32x4 __attribute__((ext_vector_type(4)));

union BF8 { unsigned short s[8]; bf16x8 v; uint4 u; };

__device__ __forceinline__ float bf2f(unsigned short u) {
    return __uint_as_float(((unsigned)u) << 16);
}
__device__ __forceinline__ unsigned short f2bf(float f) {
    unsigned x = __float_as_uint(f);
    unsigned r = (x + 0x7fffu + ((x >> 16) & 1u)) >> 16;
    return (unsigned short)r;
}
__device__ __forceinline__ void cvt2(float f, unsigned short& hi, unsigned short& lo) {
    hi = f2bf(f);
    lo = f2bf(f - bf2f(hi));
}
__device__ __forceinline__ float lrelu(float x) { return x > 0.f ? x : SLOPE * x; }

// ---------------- edge-index canonicalization (int32 vs int64 layout) --------
__global__ void detect_i64(const int* __restrict__ ei, int* __restrict__ flag) {
    int i = blockIdx.x * 256 + threadIdx.x;
    if (i < 4096) {
        if (ei[2 * i + 1] != 0) atomicOr(flag, 1);   // int64 LE high words are 0
    }
}
__global__ void canon_edges(const int* __restrict__ ei, const int* __restrict__ flag,
                            int* __restrict__ srcC, int* __restrict__ dstC) {
    int e = blockIdx.x * 256 + threadIdx.x;
    if (e >= EE) return;
    if (*flag) {               // int32 layout
        srcC[e] = ei[e];
        dstC[e] = ei[EE + e];
    } else {                   // int64 little-endian layout
        srcC[e] = ei[2 * e];
        dstC[e] = ei[2 * EE + 2 * e];
    }
}

// ---------------- CSR build: count, scan, fill ----------------
__global__ void count_deg(const int* __restrict__ dstC, int* __restrict__ deg) {
    int e = blockIdx.x * 256 + threadIdx.x;
    if (e < EE) atomicAdd(deg + dstC[e], 1);
}
__global__ void scan1(const int* __restrict__ deg, int* __restrict__ bsum) {
    __shared__ int s[256];
    int b = blockIdx.x, t = threadIdx.x;
    int base = b * 1024 + t * 4, sum = 0;
    #pragma unroll
    for (int j = 0; j < 4; j++) { int i = base + j; sum += (i < NN) ? deg[i] : 0; }
    s[t] = sum; __syncthreads();
    for (int off = 128; off > 0; off >>= 1) {
        if (t < off) s[t] += s[t + off];
        __syncthreads();
    }
    if (t == 0) bsum[b] = s[0];
}
__global__ void scan2(int* __restrict__ bsum, int* __restrict__ row_ptr) {
    if (threadIdx.x == 0 && blockIdx.x == 0) {
        int acc = 0;
        for (int i = 0; i < NB1; i++) { int v = bsum[i]; bsum[i] = acc; acc += v; }
        row_ptr[NN] = EE;
    }
}
__global__ void scan3(const int* __restrict__ deg, const int* __restrict__ bsum,
                      int* __restrict__ row_ptr, int* __restrict__ pos) {
    __shared__ int ts[256];
    int b = blockIdx.x, t = threadIdx.x;
    int base = b * 1024 + t * 4;
    int v[4], sum = 0;
    #pragma unroll
    for (int j = 0; j < 4; j++) { int i = base + j; v[j] = (i < NN) ? deg[i] : 0; sum += v[j]; }
    ts[t] = sum; __syncthreads();
    for (int off = 1; off < 256; off <<= 1) {
        int add = (t >= off) ? ts[t - off] : 0;
        __syncthreads();
        ts[t] += add;
        __syncthreads();
    }
    int prefix = bsum[b] + ts[t] - sum;          // exclusive prefix for this thread
    #pragma unroll
    for (int j = 0; j < 4; j++) {
        int i = base + j;
        if (i < NN) { row_ptr[i] = prefix; pos[i] = prefix; prefix += v[j]; }
    }
}
__global__ void fill_csr(const int* __restrict__ srcC, const int* __restrict__ dstC,
                         int* __restrict__ pos, int* __restrict__ eadj) {
    int e = blockIdx.x * 256 + threadIdx.x;
    if (e >= EE) return;
    int idx = atomicAdd(pos + dstC[e], 1);
    eadj[idx] = srcC[e];
}

// ---------------- W1 prep: fp32 [512,256] -> hi/lo bf16 transposed [256,512] --
__global__ void prep_w1(const float* __restrict__ w1,
                        unsigned short* __restrict__ w1th,
                        unsigned short* __restrict__ w1tl) {
    int t = blockIdx.x * 256 + threadIdx.x;
    if (t < NFEAT * F1) {
        int k = t / F1, n = t % F1;
        unsigned short hi, lo;
        cvt2(w1[t], hi, lo);
        w1th[n * NFEAT + k] = hi;
        w1tl[n * NFEAT + k] = lo;
    }
}

// ---------------- GEMM1: h[N,256] = x[N,512] @ W1, split-bf16 MFMA -----------
// block = 4 waves x 16 rows = 64 rows; each wave computes full N=256
// (16 N-tiles in registers) so x is fetched exactly once device-wide.
__global__ __launch_bounds__(256) void gemm1_kernel(
    const float* __restrict__ x, const unsigned short* __restrict__ w1th,
    const unsigned short* __restrict__ w1tl, float* __restrict__ h) {
    int tid = threadIdx.x;
    int wave = tid >> 6, lane = tid & 63;
    int quad = lane >> 4, r = lane & 15;
    int mBase = blockIdx.x * 64 + wave * 16;
    long arow = mBase + r; if (arow > NN - 1) arow = NN - 1;
    const float* aptr = x + arow * NFEAT + quad * 8;
    const unsigned short* bh = w1th + r * NFEAT + quad * 8;
    const unsigned short* bl = w1tl + r * NFEAT + quad * 8;

    f32x4 acc[16];
    #pragma unroll
    for (int t = 0; t < 16; t++) acc[t] = {0.f, 0.f, 0.f, 0.f};

    for (int kk = 0; kk < NFEAT / 32; kk++) {
        float4 fa0 = *(const float4*)(aptr + kk * 32);
        float4 fa1 = *(const float4*)(aptr + kk * 32 + 4);
        float fa[8] = {fa0.x, fa0.y, fa0.z, fa0.w, fa1.x, fa1.y, fa1.z, fa1.w};
        BF8 ah, al;
        #pragma unroll
        for (int j = 0; j < 8; j++) {
            unsigned short hh, ll;
            cvt2(fa[j], hh, ll);
            ah.s[j] = hh; al.s[j] = ll;
        }
        #pragma unroll
        for (int t = 0; t < 16; t++) {
            BF8 vh, vl;
            vh.u = *(const uint4*)(bh + t * 16 * NFEAT + kk * 32);
            vl.u = *(const uint4*)(bl + t * 16 * NFEAT + kk * 32);
            acc[t] = __builtin_amdgcn_mfma_f32_16x16x32_bf16(ah.v, vh.v, acc[t], 0, 0, 0);
            acc[t] = __builtin_amdgcn_mfma_f32_16x16x32_bf16(al.v, vh.v, acc[t], 0, 0, 0);
            acc[t] = __builtin_amdgcn_mfma_f32_16x16x32_bf16(ah.v, vl.v, acc[t], 0, 0, 0);
        }
    }
    #pragma unroll
    for (int i = 0; i < 4; i++) {
        int m = mBase + quad * 4 + i;
        if (m < NN) {
            float* hp = h + (long)m * F1 + r;
            #pragma unroll
            for (int t = 0; t < 16; t++) hp[t * 16] = acc[t][i];
        }
    }
}

// ---------------- e_src/e_dst layer1 ----------------
__global__ __launch_bounds__(256) void escore1_kernel(
    const float* __restrict__ h, const float* __restrict__ a_src,
    const float* __restrict__ a_dst, float* __restrict__ es, float* __restrict__ ed) {
    __shared__ float As[F1], Ad[F1];
    int tid = threadIdx.x;
    As[tid] = a_src[tid];
    Ad[tid] = a_dst[tid];
    __syncthreads();
    int t = blockIdx.x * 256 + tid;
    if (t >= NN * HEADS) return;
    int n = t >> 3, hd = t & 7;
    const float* hp = h + (long)n * F1 + hd * NHID;
    float s = 0.f, d = 0.f;
    #pragma unroll
    for (int c = 0; c < NHID; c++) {
        float v = hp[c];
        s += v * As[hd * NHID + c];
        d += v * Ad[hd * NHID + c];
    }
    es[t] = s; ed[t] = d;
}

// ---------------- layer-1 fused: softmax + aggregate + bias + ELU ------------
// one wave per dst node; lane covers 4 cols (float4); head = lane>>3
__global__ __launch_bounds__(256) void gat1_fused(
    const int* __restrict__ row_ptr, const int* __restrict__ eadj,
    const float* __restrict__ es, const float* __restrict__ ed,
    const float* __restrict__ h, const float* __restrict__ b1,
    float* __restrict__ h1o) {
    int wave = threadIdx.x >> 6, lane = threadIdx.x & 63;
    int d = blockIdx.x * 4 + wave;
    if (d >= NN) return;
    int hd = lane >> 3;
    float edv = ed[d * 8 + hd];
    int beg = row_ptr[d], end = row_ptr[d + 1];

    // pass A: per-head max (self-loop included)
    float mself = lrelu(es[d * 8 + hd] + edv);
    float m = mself;
    for (int i = beg; i < end; i += 64) {
        int myid = (i + lane < end) ? eadj[i + lane] : 0;
        int cnt = min(64, end - i);
        for (int j = 0; j < cnt; j++) {
            int s = __shfl(myid, j);
            m = fmaxf(m, lrelu(es[s * 8 + hd] + edv));
        }
    }
    // pass B: accumulate den and weighted sum
    float den = __expf(mself - m);
    float4 hv = ((const float4*)(h + (long)d * F1))[lane];
    float ax = den * hv.x, ay = den * hv.y, az = den * hv.z, aw = den * hv.w;
    for (int i = beg; i < end; i += 64) {
        int myid = (i + lane < end) ? eadj[i + lane] : 0;
        int cnt = min(64, end - i);
        for (int j = 0; j < cnt; j++) {
            int s = __shfl(myid, j);
            float w = __expf(lrelu(es[s * 8 + hd] + edv) - m);
            den += w;
            float4 v = ((const float4*)(h + (long)s * F1))[lane];
            ax += w * v.x; ay += w * v.y; az += w * v.z; aw += w * v.w;
        }
    }
    float4 bb = ((const float4*)b1)[lane];
    float inv = 1.f / den;
    float rx = ax * inv + bb.x, ry = ay * inv + bb.y,
          rz = az * inv + bb.z, rw = aw * inv + bb.w;
    rx = rx > 0.f ? rx : expm1f(rx);
    ry = ry > 0.f ? ry : expm1f(ry);
    rz = rz > 0.f ? rz : expm1f(rz);
    rw = rw > 0.f ? rw : expm1f(rw);
    float4 r = {rx, ry, rz, rw};
    ((float4*)(h1o + (long)d * F1))[lane] = r;
}

// ---------------- GEMM2: h2[N,40] = h1[N,256] @ W2 (fp32, W2 in LDS) ----------
__global__ __launch_bounds__(256) void gemm2_kernel(const float* __restrict__ h1,
                                                    const float* __restrict__ w2,
                                                    float* __restrict__ h2) {
    __shared__ float Ws[F1 * NCLASS];
    for (int i = threadIdx.x; i < F1 * NCLASS; i += 256) Ws[i] = w2[i];
    __syncthreads();
    long t = (long)blockIdx.x * 256 + threadIdx.x;
    if (t >= (long)NN * NCLASS) return;
    int n = (int)(t / NCLASS);
    int c = (int)(t - (long)n * NCLASS);
    const float* hp = h1 + (long)n * F1;
    float acc = 0.f;
    #pragma unroll 8
    for (int k = 0; k < F1; k++) acc += hp[k] * Ws[k * NCLASS + c];
    h2[t] = acc;
}

// ---------------- e_src/e_dst layer2 ----------------
__global__ void escore2_kernel(const float* __restrict__ h2,
                               const float* __restrict__ a_src2,
                               const float* __restrict__ a_dst2,
                               float* __restrict__ e2s, float* __restrict__ e2d) {
    __shared__ float As[NCLASS], Ad[NCLASS];
    if (threadIdx.x < NCLASS) {
        As[threadIdx.x] = a_src2[threadIdx.x];
        Ad[threadIdx.x] = a_dst2[threadIdx.x];
    }
    __syncthreads();
    int n = blockIdx.x * 256 + threadIdx.x;
    if (n >= NN) return;
    const float* hp = h2 + (long)n * NCLASS;
    float s = 0.f, d = 0.f;
    #pragma unroll
    for (int c = 0; c < NCLASS; c++) {
        float v = hp[c];
        s += v * As[c];
        d += v * Ad[c];
    }
    e2s[n] = s; e2d[n] = d;
}

// ---------------- layer-2 fused: softmax-agg + bias + log_softmax ------------
// one wave per dst node; lanes 0..39 hold classes
__global__ __launch_bounds__(256) void gat2_logsm(
    const int* __restrict__ row_ptr, const int* __restrict__ eadj,
    const float* __restrict__ e2s, const float* __restrict__ e2d,
    const float* __restrict__ h2, const float* __restrict__ b2,
    float* __restrict__ out0) {
    int wave = threadIdx.x >> 6, lane = threadIdx.x & 63;
    int d = blockIdx.x * 4 + wave;
    if (d >= NN) return;
    float edv = e2d[d];
    int beg = row_ptr[d], end = row_ptr[d + 1];

    float mself = lrelu(e2s[d] + edv);
    float m = mself;
    for (int i = beg; i < end; i += 64) {
        int myid = (i + lane < end) ? eadj[i + lane] : 0;
        int cnt = min(64, end - i);
        for (int j = 0; j < cnt; j++) {
            int s = __shfl(myid, j);
            m = fmaxf(m, lrelu(e2s[s] + edv));
        }
    }
    float den = __expf(mself - m);
    float acc = (lane < NCLASS) ? den * h2[(long)d * NCLASS + lane] : 0.f;
    for (int i = beg; i < end; i += 64) {
        int myid = (i + lane < end) ? eadj[i + lane] : 0;
        int cnt = min(64, end - i);
        for (int j = 0; j < cnt; j++) {
            int s = __shfl(myid, j);
            float w = __expf(lrelu(e2s[s] + edv) - m);
            den += w;
            if (lane < NCLASS) acc += w * h2[(long)s * NCLASS + lane];
        }
    }
    float v = (lane < NCLASS) ? acc / den + b2[lane] : -1e30f;
    float mx = v;
    #pragma unroll
    for (int off = 32; off; off >>= 1) mx = fmaxf(mx, __shfl_xor(mx, off));
    float ex = (lane < NCLASS) ? __expf(v - mx) : 0.f;
    float sm = ex;
    #pragma unroll
    for (int off = 32; off; off >>= 1) sm += __shfl_xor(sm, off);
    float ls = mx + logf(sm);
    if (lane < NCLASS) out0[(long)d * NCLASS + lane] = v - ls;
}

extern "C" void kernel_launch(void* const* d_in, const int* in_sizes, int n_in,
                              void* d_out, int out_size, void* d_ws, size_t ws_size,
                              hipStream_t stream) {
    const float* x   = (const float*)d_in[0];
    const int* ei    = (const int*)d_in[1];
    const float* W1  = (const float*)d_in[2];
    const float* as1 = (const float*)d_in[3];
    const float* ad1 = (const float*)d_in[4];
    const float* b1  = (const float*)d_in[5];
    const float* W2  = (const float*)d_in[6];
    const float* as2 = (const float*)d_in[7];
    const float* ad2 = (const float*)d_in[8];
    const float* b2  = (const float*)d_in[9];

    float* out0 = (float*)d_out;                   // [N,40] log_softmax
    float* h1o  = out0 + (long)NN * NCLASS;        // [N,256] h1 (fp32)

    // workspace layout
    float* h    = (float*)d_ws;                               // N*F1 fp32 (102.4 MB)
    unsigned short* w1th = (unsigned short*)(h + (long)NN * F1);   // 512*256 bf16
    unsigned short* w1tl = w1th + NFEAT * F1;
    float* es1  = (float*)(w1tl + NFEAT * F1);                // N*8
    float* ed1  = es1 + NN * HEADS;
    float* e2s  = ed1 + NN * HEADS;                           // N
    float* e2d  = e2s + NN;
    int* srcC   = (int*)(e2d + NN);                           // E
    int* dstC   = srcC + EE;                                  // E
    int* eadj   = dstC + EE;                                  // E
    int* deg    = eadj + EE;                                  // N
    int* row_ptr= deg + NN;                                   // N+1
    int* pos    = row_ptr + NN + 1;                           // N
    int* bsum   = pos + NN;                                   // NB1
    int* flag   = bsum + NB1;                                 // 1
    float* h2   = h;                                          // alias: N*40 (h dead after gat1)

    hipMemsetAsync(flag, 0, 4, stream);
    hipMemsetAsync(deg, 0, (size_t)NN * 4, stream);

    // edge canonicalization + CSR build
    detect_i64<<<16, 256, 0, stream>>>(ei, flag);
    canon_edges<<<(EE + 255) / 256, 256, 0, stream>>>(ei, flag, srcC, dstC);
    count_deg<<<(EE + 255) / 256, 256, 0, stream>>>(dstC, deg);
    scan1<<<NB1, 256, 0, stream>>>(deg, bsum);
    scan2<<<1, 64, 0, stream>>>(bsum, row_ptr);
    scan3<<<NB1, 256, 0, stream>>>(deg, bsum, row_ptr, pos);
    fill_csr<<<(EE + 255) / 256, 256, 0, stream>>>(srcC, dstC, pos, eadj);

    // layer 1
    prep_w1<<<(NFEAT * F1 + 255) / 256, 256, 0, stream>>>(W1, w1th, w1tl);
    gemm1_kernel<<<(NN + 63) / 64, 256, 0, stream>>>(x, w1th, w1tl, h);
    escore1_kernel<<<(NN * HEADS) / 256, 256, 0, stream>>>(h, as1, ad1, es1, ed1);
    gat1_fused<<<(NN + 3) / 4, 256, 0, stream>>>(row_ptr, eadj, es1, ed1, h, b1, h1o);

    // layer 2
    gemm2_kernel<<<(int)(((long)NN * NCLASS + 255) / 256), 256, 0, stream>>>(h1o, W2, h2);
    escore2_kernel<<<(NN + 255) / 256, 256, 0, stream>>>(h2, as2, ad2, e2s, e2d);
    gat2_logsm<<<(NN + 3) / 4, 256, 0, stream>>>(row_ptr, eadj, e2s, e2d, h2, b2, out0);
}

// Round 5
// 762.888 us; speedup vs baseline: 1.8421x; 1.8421x over previous
//
#include <hip/hip_runtime.h>

#define NN 100000
#define EE 1000000
#define NFEAT 512
#define NHID 32
#define HEADS 8
#define F1 256               // HEADS*NHID
#define NCLASS 40
#define SLOPE 0.2f
#define NB1 98               // ceil(NN/1024) scan blocks

typedef __bf16 bf16x8 __attribute__((ext_vector_type(8)));
typedef float f32x4 __attribute__((ext_vector_type(4)));

union BF8 { unsigned short s[8]; bf16x8 v; uint4 u; };

__device__ __forceinline__ float bf2f(unsigned short u) {
    return __uint_as_float(((unsigned)u) << 16);
}
__device__ __forceinline__ unsigned short f2bf(float f) {
    unsigned x = __float_as_uint(f);
    unsigned r = (x + 0x7fffu + ((x >> 16) & 1u)) >> 16;
    return (unsigned short)r;
}
__device__ __forceinline__ float lrelu(float x) { return x > 0.f ? x : SLOPE * x; }

// ---------------- edge-index canonicalization (int32 vs int64 layout) --------
__global__ void detect_i64(const int* __restrict__ ei, int* __restrict__ flag) {
    int i = blockIdx.x * 256 + threadIdx.x;
    if (i < 4096) {
        if (ei[2 * i + 1] != 0) atomicOr(flag, 1);   // int64 LE high words are 0
    }
}
__global__ void canon_edges(const int* __restrict__ ei, const int* __restrict__ flag,
                            int* __restrict__ srcC, int* __restrict__ dstC) {
    int e = blockIdx.x * 256 + threadIdx.x;
    if (e >= EE) return;
    if (*flag) {               // int32 layout
        srcC[e] = ei[e];
        dstC[e] = ei[EE + e];
    } else {                   // int64 little-endian layout
        srcC[e] = ei[2 * e];
        dstC[e] = ei[2 * EE + 2 * e];
    }
}

// ---------------- CSR build: count, scan, fill ----------------
__global__ void count_deg(const int* __restrict__ dstC, int* __restrict__ deg) {
    int e = blockIdx.x * 256 + threadIdx.x;
    if (e < EE) atomicAdd(deg + dstC[e], 1);
}
__global__ void scan1(const int* __restrict__ deg, int* __restrict__ bsum) {
    __shared__ int s[256];
    int b = blockIdx.x, t = threadIdx.x;
    int base = b * 1024 + t * 4, sum = 0;
    #pragma unroll
    for (int j = 0; j < 4; j++) { int i = base + j; sum += (i < NN) ? deg[i] : 0; }
    s[t] = sum; __syncthreads();
    for (int off = 128; off > 0; off >>= 1) {
        if (t < off) s[t] += s[t + off];
        __syncthreads();
    }
    if (t == 0) bsum[b] = s[0];
}
__global__ void scan2(int* __restrict__ bsum, int* __restrict__ row_ptr) {
    if (threadIdx.x == 0 && blockIdx.x == 0) {
        int acc = 0;
        for (int i = 0; i < NB1; i++) { int v = bsum[i]; bsum[i] = acc; acc += v; }
        row_ptr[NN] = EE;
    }
}
__global__ void scan3(const int* __restrict__ deg, const int* __restrict__ bsum,
                      int* __restrict__ row_ptr, int* __restrict__ pos) {
    __shared__ int ts[256];
    int b = blockIdx.x, t = threadIdx.x;
    int base = b * 1024 + t * 4;
    int v[4], sum = 0;
    #pragma unroll
    for (int j = 0; j < 4; j++) { int i = base + j; v[j] = (i < NN) ? deg[i] : 0; sum += v[j]; }
    ts[t] = sum; __syncthreads();
    for (int off = 1; off < 256; off <<= 1) {
        int add = (t >= off) ? ts[t - off] : 0;
        __syncthreads();
        ts[t] += add;
        __syncthreads();
    }
    int prefix = bsum[b] + ts[t] - sum;          // exclusive prefix for this thread
    #pragma unroll
    for (int j = 0; j < 4; j++) {
        int i = base + j;
        if (i < NN) { row_ptr[i] = prefix; pos[i] = prefix; prefix += v[j]; }
    }
}
__global__ void fill_csr(const int* __restrict__ srcC, const int* __restrict__ dstC,
                         int* __restrict__ pos, int* __restrict__ eadj) {
    int e = blockIdx.x * 256 + threadIdx.x;
    if (e >= EE) return;
    int idx = atomicAdd(pos + dstC[e], 1);
    eadj[idx] = srcC[e];
}

// ---------------- W1 prep: fp32 [512,256] -> bf16 transposed [256,512] -------
__global__ void prep_w1(const float* __restrict__ w1, unsigned short* __restrict__ w1tb) {
    int t = blockIdx.x * 256 + threadIdx.x;
    if (t < NFEAT * F1) {
        int k = t / F1, n = t % F1;
        w1tb[n * NFEAT + k] = f2bf(w1[t]);
    }
}

// ---------------- GEMM1: hb[N,256] = x[N,512] @ W1 (bf16 MFMA, LDS-staged B) --
// block = 4 waves x 16 rows = 64 rows; per k-step the 16KB B slice is staged
// into LDS via global_load_lds (double-buffered), shared by all 4 waves.
// LDS layout: Bs[n*32 + k_in_slice] (bf16) — matches the wave-uniform+lane*16
// constraint of global_load_lds (chunk c = j*256+tid -> lds byte c*16).
__device__ __forceinline__ void stage_b(const unsigned short* __restrict__ w1tb,
                                        unsigned short* bs, int kk, int tid) {
    #pragma unroll
    for (int j = 0; j < 4; j++) {
        int c = j * 256 + tid;
        int n = c >> 2, part = c & 3;
        const unsigned short* src = w1tb + n * NFEAT + kk * 32 + part * 8;
        unsigned short* dst = bs + c * 8;
        __builtin_amdgcn_global_load_lds(
            (const __attribute__((address_space(1))) unsigned int*)src,
            (__attribute__((address_space(3))) unsigned int*)dst, 16, 0, 0);
    }
}

__global__ __launch_bounds__(256) void gemm1_kernel(
    const float* __restrict__ x, const unsigned short* __restrict__ w1tb,
    unsigned short* __restrict__ hb) {
    __shared__ unsigned short Bs[2][256 * 32];   // 2 x 16 KB
    int tid = threadIdx.x;
    int wave = tid >> 6, lane = tid & 63;
    int quad = lane >> 4, r = lane & 15;
    int mBase = blockIdx.x * 64 + wave * 16;
    long arow = mBase + r; if (arow > NN - 1) arow = NN - 1;
    const float* aptr = x + arow * NFEAT + quad * 8;

    stage_b(w1tb, Bs[0], 0, tid);

    f32x4 acc[16];
    #pragma unroll
    for (int t = 0; t < 16; t++) acc[t] = {0.f, 0.f, 0.f, 0.f};

    for (int kk = 0; kk < 16; kk++) {
        float4 fa0 = *(const float4*)(aptr + kk * 32);
        float4 fa1 = *(const float4*)(aptr + kk * 32 + 4);
        float fa[8] = {fa0.x, fa0.y, fa0.z, fa0.w, fa1.x, fa1.y, fa1.z, fa1.w};
        BF8 ah;
        #pragma unroll
        for (int j = 0; j < 8; j++) ah.s[j] = f2bf(fa[j]);
        __syncthreads();                          // Bs[kk&1] staged; prior reads done
        if (kk + 1 < 16) stage_b(w1tb, Bs[(kk + 1) & 1], kk + 1, tid);
        const unsigned short* bsc = Bs[kk & 1];
        #pragma unroll
        for (int t = 0; t < 16; t++) {
            BF8 vb;
            vb.u = *(const uint4*)(bsc + (t * 16 + r) * 32 + quad * 8);
            acc[t] = __builtin_amdgcn_mfma_f32_16x16x32_bf16(ah.v, vb.v, acc[t], 0, 0, 0);
        }
    }
    #pragma unroll
    for (int i = 0; i < 4; i++) {
        int m = mBase + quad * 4 + i;
        if (m < NN) {
            unsigned short* hp = hb + (long)m * F1 + r;
            #pragma unroll
            for (int t = 0; t < 16; t++) hp[t * 16] = f2bf(acc[t][i]);
        }
    }
}

// ---------------- e_src/e_dst layer1 (bf16 h input) ----------------
__global__ __launch_bounds__(256) void escore1_kernel(
    const unsigned short* __restrict__ hb, const float* __restrict__ a_src,
    const float* __restrict__ a_dst, float* __restrict__ es, float* __restrict__ ed) {
    __shared__ float As[F1], Ad[F1];
    int tid = threadIdx.x;
    As[tid] = a_src[tid];
    Ad[tid] = a_dst[tid];
    __syncthreads();
    int t = blockIdx.x * 256 + tid;
    if (t >= NN * HEADS) return;
    int n = t >> 3, hd = t & 7;
    const uint4* hp = (const uint4*)(hb + (long)n * F1 + hd * NHID);
    float s = 0.f, d = 0.f;
    #pragma unroll
    for (int q = 0; q < 4; q++) {
        uint4 u = hp[q];
        unsigned vv[4] = {u.x, u.y, u.z, u.w};
        #pragma unroll
        for (int w = 0; w < 4; w++) {
            float lo = bf2f((unsigned short)(vv[w] & 0xffffu));
            float hi = bf2f((unsigned short)(vv[w] >> 16));
            int c = q * 8 + w * 2;
            s += lo * As[hd * NHID + c] + hi * As[hd * NHID + c + 1];
            d += lo * Ad[hd * NHID + c] + hi * Ad[hd * NHID + c + 1];
        }
    }
    es[t] = s; ed[t] = d;
}

// ---------------- layer-1 fused: softmax + aggregate + bias + ELU ------------
// one wave per dst node. Score lanes: (eslot = lane>>3, hd8 = lane&7) -> 8
// edges x 8 heads in parallel; shuffle-reduce over eslot bits (8,16,32).
// Output lanes: lane covers cols lane*4..+4 (head hdo = lane>>3).
__global__ __launch_bounds__(256) void gat1_fused(
    const int* __restrict__ row_ptr, const int* __restrict__ eadj,
    const float* __restrict__ es, const float* __restrict__ ed,
    const unsigned short* __restrict__ hb, const float* __restrict__ b1,
    float* __restrict__ h1o) {
    int wave = threadIdx.x >> 6, lane = threadIdx.x & 63;
    int d = blockIdx.x * 4 + wave;
    if (d >= NN) return;
    int eslot = lane >> 3, hd8 = lane & 7, hdo = lane >> 3;
    float edv = ed[d * 8 + hd8];
    int beg = row_ptr[d], end = row_ptr[d + 1];

    // pass A: per-head max, 8 edges in parallel
    float mself = lrelu(es[d * 8 + hd8] + edv);
    float m = mself;
    for (int i = beg; i < end; i += 8) {
        int idx = i + eslot;
        int s = (idx < end) ? eadj[idx] : 0;
        float el = lrelu(es[s * 8 + hd8] + edv);
        if (idx >= end) el = -1e30f;
        m = fmaxf(m, el);
    }
    m = fmaxf(m, __shfl_xor(m, 8));
    m = fmaxf(m, __shfl_xor(m, 16));
    m = fmaxf(m, __shfl_xor(m, 32));

    // pass B+C fused: den + weighted row gather
    float wself = __expf(mself - m);
    float den = (eslot == 0) ? wself : 0.f;
    float wselfo = __shfl(wself, hdo);
    ushort4 hv = ((const ushort4*)(hb + (long)d * F1))[lane];
    float ax = wselfo * bf2f(hv.x), ay = wselfo * bf2f(hv.y);
    float az = wselfo * bf2f(hv.z), aw = wselfo * bf2f(hv.w);

    for (int i = beg; i < end; i += 8) {
        int idx = i + eslot;
        int s = (idx < end) ? eadj[idx] : 0;
        float el = lrelu(es[s * 8 + hd8] + edv);
        float wj = (idx < end) ? __expf(el - m) : 0.f;
        den += wj;
        int cnt = min(8, end - i);
        if (cnt == 8) {
            #pragma unroll
            for (int j = 0; j < 8; j++) {
                float w = __shfl(wj, j * 8 + hdo);
                int sj = __shfl(s, j * 8);
                ushort4 v = ((const ushort4*)(hb + (long)sj * F1))[lane];
                ax += w * bf2f(v.x); ay += w * bf2f(v.y);
                az += w * bf2f(v.z); aw += w * bf2f(v.w);
            }
        } else {
            for (int j = 0; j < cnt; j++) {
                float w = __shfl(wj, j * 8 + hdo);
                int sj = __shfl(s, j * 8);
                ushort4 v = ((const ushort4*)(hb + (long)sj * F1))[lane];
                ax += w * bf2f(v.x); ay += w * bf2f(v.y);
                az += w * bf2f(v.z); aw += w * bf2f(v.w);
            }
        }
    }
    den += __shfl_xor(den, 8);
    den += __shfl_xor(den, 16);
    den += __shfl_xor(den, 32);
    float deno = __shfl(den, hdo);

    float4 bb = ((const float4*)b1)[lane];
    float inv = 1.f / deno;
    float rx = ax * inv + bb.x, ry = ay * inv + bb.y;
    float rz = az * inv + bb.z, rw = aw * inv + bb.w;
    rx = rx > 0.f ? rx : expm1f(rx);
    ry = ry > 0.f ? ry : expm1f(ry);
    rz = rz > 0.f ? rz : expm1f(rz);
    rw = rw > 0.f ? rw : expm1f(rw);
    float4 r = {rx, ry, rz, rw};
    ((float4*)(h1o + (long)d * F1))[lane] = r;
}

// ---------------- GEMM2: h2[N,40] = h1[N,256] @ W2 (fp32, W2 in LDS) ----------
// thread -> (node, 4-class chunk); float4 row loads, float4 LDS weights
__global__ __launch_bounds__(256) void gemm2_kernel(const float* __restrict__ h1,
                                                    const float* __restrict__ w2,
                                                    float* __restrict__ h2) {
    __shared__ float4 Ws[F1 * 10];
    for (int i = threadIdx.x; i < F1 * 10; i += 256) Ws[i] = ((const float4*)w2)[i];
    __syncthreads();
    long t = (long)blockIdx.x * 256 + threadIdx.x;
    if (t >= (long)NN * 10) return;
    int n = (int)(t / 10);
    int j = (int)(t - (long)n * 10);
    const float4* hp = (const float4*)(h1 + (long)n * F1);
    float4 a = {0.f, 0.f, 0.f, 0.f};
    #pragma unroll 8
    for (int k4 = 0; k4 < 64; k4++) {
        float4 hv = hp[k4];
        float4 w0 = Ws[(k4 * 4 + 0) * 10 + j];
        float4 w1v = Ws[(k4 * 4 + 1) * 10 + j];
        float4 w2v = Ws[(k4 * 4 + 2) * 10 + j];
        float4 w3v = Ws[(k4 * 4 + 3) * 10 + j];
        a.x += hv.x * w0.x + hv.y * w1v.x + hv.z * w2v.x + hv.w * w3v.x;
        a.y += hv.x * w0.y + hv.y * w1v.y + hv.z * w2v.y + hv.w * w3v.y;
        a.z += hv.x * w0.z + hv.y * w1v.z + hv.z * w2v.z + hv.w * w3v.z;
        a.w += hv.x * w0.w + hv.y * w1v.w + hv.z * w2v.w + hv.w * w3v.w;
    }
    ((float4*)(h2 + (long)n * NCLASS))[j] = a;
}

// ---------------- e_src/e_dst layer2 ----------------
__global__ void escore2_kernel(const float* __restrict__ h2,
                               const float* __restrict__ a_src2,
                               const float* __restrict__ a_dst2,
                               float* __restrict__ e2s, float* __restrict__ e2d) {
    __shared__ float As[NCLASS], Ad[NCLASS];
    if (threadIdx.x < NCLASS) {
        As[threadIdx.x] = a_src2[threadIdx.x];
        Ad[threadIdx.x] = a_dst2[threadIdx.x];
    }
    __syncthreads();
    int n = blockIdx.x * 256 + threadIdx.x;
    if (n >= NN) return;
    const float* hp = h2 + (long)n * NCLASS;
    float s = 0.f, d = 0.f;
    #pragma unroll
    for (int c = 0; c < NCLASS; c++) {
        float v = hp[c];
        s += v * As[c];
        d += v * Ad[c];
    }
    e2s[n] = s; e2d[n] = d;
}

// ---------------- layer-2 fused: softmax-agg + bias + log_softmax ------------
__global__ __launch_bounds__(256) void gat2_logsm(
    const int* __restrict__ row_ptr, const int* __restrict__ eadj,
    const float* __restrict__ e2s, const float* __restrict__ e2d,
    const float* __restrict__ h2, const float* __restrict__ b2,
    float* __restrict__ out0) {
    int wave = threadIdx.x >> 6, lane = threadIdx.x & 63;
    int d = blockIdx.x * 4 + wave;
    if (d >= NN) return;
    float edv = e2d[d];
    int beg = row_ptr[d], end = row_ptr[d + 1];

    float mself = lrelu(e2s[d] + edv);
    float m = mself;
    for (int i = beg; i < end; i += 64) {
        int idx = i + lane;
        int s = (idx < end) ? eadj[idx] : 0;
        float el = lrelu(e2s[s] + edv);
        if (idx >= end) el = -1e30f;
        m = fmaxf(m, el);
    }
    #pragma unroll
    for (int off = 32; off; off >>= 1) m = fmaxf(m, __shfl_xor(m, off));

    float den = __expf(mself - m);
    float acc = (lane < NCLASS) ? den * h2[(long)d * NCLASS + lane] : 0.f;
    for (int i = beg; i < end; i += 64) {
        int idx = i + lane;
        int s = (idx < end) ? eadj[idx] : 0;
        float el = lrelu(e2s[s] + edv);
        float wj = (idx < end) ? __expf(el - m) : 0.f;
        int cnt = min(64, end - i);
        for (int j = 0; j < cnt; j++) {
            float w = __shfl(wj, j);
            int sj = __shfl(s, j);
            if (lane < NCLASS) acc += w * h2[(long)sj * NCLASS + lane];
        }
        // per-lane den partials; reduce once after the loop
        den += wj;
    }
    // den currently: exp(self) in every lane + per-lane partials -> fix: reduce partials only
    // (self term was added in every lane; subtract 63 extra copies after reduction)
    float dpart = den;
    #pragma unroll
    for (int off = 32; off; off >>= 1) dpart += __shfl_xor(dpart, off);
    float dfull = dpart - 63.f * __expf(mself - m);

    float v = (lane < NCLASS) ? acc / dfull + b2[lane] : -1e30f;
    float mx = v;
    #pragma unroll
    for (int off = 32; off; off >>= 1) mx = fmaxf(mx, __shfl_xor(mx, off));
    float ex = (lane < NCLASS) ? __expf(v - mx) : 0.f;
    float sm = ex;
    #pragma unroll
    for (int off = 32; off; off >>= 1) sm += __shfl_xor(sm, off);
    float ls = mx + logf(sm);
    if (lane < NCLASS) out0[(long)d * NCLASS + lane] = v - ls;
}

extern "C" void kernel_launch(void* const* d_in, const int* in_sizes, int n_in,
                              void* d_out, int out_size, void* d_ws, size_t ws_size,
                              hipStream_t stream) {
    const float* x   = (const float*)d_in[0];
    const int* ei    = (const int*)d_in[1];
    const float* W1  = (const float*)d_in[2];
    const float* as1 = (const float*)d_in[3];
    const float* ad1 = (const float*)d_in[4];
    const float* b1  = (const float*)d_in[5];
    const float* W2  = (const float*)d_in[6];
    const float* as2 = (const float*)d_in[7];
    const float* ad2 = (const float*)d_in[8];
    const float* b2  = (const float*)d_in[9];

    float* out0 = (float*)d_out;                   // [N,40] log_softmax
    float* h1o  = out0 + (long)NN * NCLASS;        // [N,256] h1 (fp32)

    // workspace layout
    unsigned short* hb = (unsigned short*)d_ws;               // N*F1 bf16 (51.2 MB)
    unsigned short* w1tb = hb + (long)NN * F1;                // 256*512 bf16
    float* es1  = (float*)(w1tb + F1 * NFEAT);                // N*8
    float* ed1  = es1 + NN * HEADS;
    float* e2s  = ed1 + NN * HEADS;                           // N
    float* e2d  = e2s + NN;
    int* srcC   = (int*)(e2d + NN);                           // E
    int* dstC   = srcC + EE;                                  // E
    int* eadj   = dstC + EE;                                  // E
    int* deg    = eadj + EE;                                  // N
    int* row_ptr= deg + NN;                                   // N+1
    int* pos    = row_ptr + NN + 1;                           // N
    int* bsum   = pos + NN;                                   // NB1
    int* flag   = bsum + NB1;                                 // 1
    float* h2   = (float*)d_ws;                               // alias: N*40 (hb dead after gat1)

    hipMemsetAsync(flag, 0, 4, stream);
    hipMemsetAsync(deg, 0, (size_t)NN * 4, stream);

    // edge canonicalization + CSR build
    detect_i64<<<16, 256, 0, stream>>>(ei, flag);
    canon_edges<<<(EE + 255) / 256, 256, 0, stream>>>(ei, flag, srcC, dstC);
    count_deg<<<(EE + 255) / 256, 256, 0, stream>>>(dstC, deg);
    scan1<<<NB1, 256, 0, stream>>>(deg, bsum);
    scan2<<<1, 64, 0, stream>>>(bsum, row_ptr);
    scan3<<<NB1, 256, 0, stream>>>(deg, bsum, row_ptr, pos);
    fill_csr<<<(EE + 255) / 256, 256, 0, stream>>>(srcC, dstC, pos, eadj);

    // layer 1
    prep_w1<<<(NFEAT * F1 + 255) / 256, 256, 0, stream>>>(W1, w1tb);
    gemm1_kernel<<<(NN + 63) / 64, 256, 0, stream>>>(x, w1tb, hb);
    escore1_kernel<<<(NN * HEADS) / 256, 256, 0, stream>>>(hb, as1, ad1, es1, ed1);
    gat1_fused<<<(NN + 3) / 4, 256, 0, stream>>>(row_ptr, eadj, es1, ed1, hb, b1, h1o);

    // layer 2
    gemm2_kernel<<<(int)(((long)NN * 10 + 255) / 256), 256, 0, stream>>>(h1o, W2, h2);
    escore2_kernel<<<(NN + 255) / 256, 256, 0, stream>>>(h2, as2, ad2, e2s, e2d);
    gat2_logsm<<<(NN + 3) / 4, 256, 0, stream>>>(row_ptr, eadj, e2s, e2d, h2, b2, out0);
}